// Round 1
// baseline (180.847 us; speedup 1.0000x reference)
//
#include <hip/hip_runtime.h>

#define H 5
#define IN_SIZE 128
#define OUT_SIZE 128
#define BATCH 2048

// silu(p) = p * sigmoid(p) = p / (1 + exp(-p))
// exp(-p) = exp2(-p * log2(e)) -> single v_exp_f32 (neg folds into the mul)
// 1/(1+e) -> single v_rcp_f32 (~1 ulp, fine vs 7.4e-5 abs threshold)
__device__ __forceinline__ float silu_f(float p) {
    float e = __builtin_amdgcn_exp2f(p * -1.44269504088896340736f);
    float r = __builtin_amdgcn_rcpf(1.0f + e);
    return p * r;
}

// Grid: (OUT_SIZE, BATCH/256); block: 256 threads.
// Each block: fixed output column o, 256 batch rows. Each thread owns one
// batch row b and loops over the 128 input features i; net n = i*128 + o.
// All weight addresses are wave-uniform (o from blockIdx, i from the loop)
// -> compiler emits s_load into SGPRs; weights never touch the vector pipes.
__global__ __launch_bounds__(256) void mlpkan_kernel(
    const float* __restrict__ x,
    const float* __restrict__ W0, const float* __restrict__ b0,
    const float* __restrict__ W1, const float* __restrict__ b1,
    const float* __restrict__ W2, const float* __restrict__ b2,
    float* __restrict__ out)
{
    const int o = blockIdx.x;                           // 0..127
    const int b = blockIdx.y * 256 + threadIdx.x;       // batch row
    const float* xrow = x + b * IN_SIZE;

    float acc = 0.0f;

    #pragma unroll 1
    for (int i = 0; i < IN_SIZE; i += 4) {
        // 16B per-lane load of this thread's x[b, i:i+4]
        float4 xv = *(const float4*)(xrow + i);
        float xs[4] = {xv.x, xv.y, xv.z, xv.w};

        #pragma unroll
        for (int ii = 0; ii < 4; ++ii) {
            const int n = (i + ii) * OUT_SIZE + o;      // wave-uniform
            const float* w0  = W0 + n * H;
            const float* bb0 = b0 + n * H;
            const float* w1  = W1 + n * (H * H);
            const float* bb1 = b1 + n * H;
            const float* w2  = W2 + n * H;
            const float  xi  = xs[ii];

            // layer 0: 1 -> H, silu
            float h1[H];
            #pragma unroll
            for (int j = 0; j < H; ++j)
                h1[j] = silu_f(fmaf(w0[j], xi, bb0[j]));

            // layer 1: H -> H, silu
            float h2[H];
            #pragma unroll
            for (int k = 0; k < H; ++k) {
                float p = bb1[k];
                #pragma unroll
                for (int j = 0; j < H; ++j)
                    p = fmaf(w1[k * H + j], h1[j], p);
                h2[k] = silu_f(p);
            }

            // layer 2: H -> 1, linear; accumulate over i
            float y = b2[n];
            #pragma unroll
            for (int k = 0; k < H; ++k)
                y = fmaf(w2[k], h2[k], y);
            acc += y;
        }
    }

    // out[b, o], row-major (B, OUT_SIZE)
    out[b * OUT_SIZE + o] = acc;
}

extern "C" void kernel_launch(void* const* d_in, const int* in_sizes, int n_in,
                              void* d_out, int out_size, void* d_ws, size_t ws_size,
                              hipStream_t stream) {
    const float* x  = (const float*)d_in[0];
    const float* W0 = (const float*)d_in[1];
    const float* b0 = (const float*)d_in[2];
    const float* W1 = (const float*)d_in[3];
    const float* b1 = (const float*)d_in[4];
    const float* W2 = (const float*)d_in[5];
    const float* b2 = (const float*)d_in[6];
    float* out = (float*)d_out;

    dim3 grid(OUT_SIZE, BATCH / 256);
    dim3 block(256);
    mlpkan_kernel<<<grid, block, 0, stream>>>(x, W0, b0, W1, b1, W2, b2, out);
}